// Round 1
// baseline (4669.261 us; speedup 1.0000x reference)
//
#include <hip/hip_runtime.h>
#include <math.h>

#define B_  1024
#define S_  100
#define H_  256
#define L_  20000
#define U_  20000
#define EL_ 500000
#define EU_ 400000

// ---------------- flags for needed user rows ----------------
__global__ void k_mark(const int* __restrict__ uid, int* __restrict__ flags) {
    int i = blockIdx.x * blockDim.x + threadIdx.x;
    if (i < B_) flags[uid[i]] = 1;
}

// ---------------- COO segment-sum scatter: out[row] += val * emb[col] ----------------
// 32 threads per edge, 8 floats each.
__global__ void k_scatter(const int* __restrict__ row, const int* __restrict__ col,
                          const float* __restrict__ vals, const float* __restrict__ emb,
                          float* __restrict__ out, const int* __restrict__ flags, int nE) {
    long long tid = (long long)blockIdx.x * blockDim.x + threadIdx.x;
    int e = (int)(tid >> 5);
    if (e >= nE) return;
    int r = row[e];
    if (flags && !flags[r]) return;
    int part = (int)(tid & 31);
    int c = col[e];
    float v = vals[e];
    int h0 = part * 8;
    const float4* s4 = (const float4*)(emb + (long long)c * H_ + h0);
    float4 x0 = s4[0], x1 = s4[1];
    float* dst = out + (long long)r * H_ + h0;
    atomicAdd(dst + 0, v * x0.x); atomicAdd(dst + 1, v * x0.y);
    atomicAdd(dst + 2, v * x0.z); atomicAdd(dst + 3, v * x0.w);
    atomicAdd(dst + 4, v * x1.x); atomicAdd(dst + 5, v * x1.y);
    atomicAdd(dst + 6, v * x1.z); atomicAdd(dst + 7, v * x1.w);
}

// ---------------- generic f32 GEMM: C[m,n] = sum_k A[m,k]*Bm[n,k] + bias1[n] + bias2[n] ----------------
// 128x128 tile, BK=16, 256 threads, 8x8 per thread.
#define BM 128
#define BN 128
#define BK 16
#define PADW 132   // 132*4B = 528B row stride, 16B aligned

__global__ __launch_bounds__(256) void k_gemm(
        const float* __restrict__ A, const float* __restrict__ Bm,
        const float* __restrict__ bias1, const float* __restrict__ bias2,
        float* __restrict__ C, int M, int N, int K) {
    __shared__ float As[BK][PADW];
    __shared__ float Bs[BK][PADW];
    int m0 = blockIdx.x * BM;
    int n0 = blockIdx.y * BN;
    int tid = threadIdx.x;
    int tn = tid & 15, tm = tid >> 4;

    float acc[8][8];
#pragma unroll
    for (int i = 0; i < 8; i++)
#pragma unroll
        for (int j = 0; j < 8; j++) acc[i][j] = 0.f;

    // two float4 loads from each of A,B per chunk: v0=tid, v1=tid+256
    for (int k0 = 0; k0 < K; k0 += BK) {
#pragma unroll
        for (int h = 0; h < 2; h++) {
            int v = tid + h * 256;
            int rw = v >> 2, c4 = v & 3;
            int ar = m0 + rw; if (ar > M - 1) ar = M - 1;
            float4 a = *(const float4*)(A + (long long)ar * K + k0 + c4 * 4);
            As[c4 * 4 + 0][rw] = a.x; As[c4 * 4 + 1][rw] = a.y;
            As[c4 * 4 + 2][rw] = a.z; As[c4 * 4 + 3][rw] = a.w;
            int br = n0 + rw; if (br > N - 1) br = N - 1;
            float4 b = *(const float4*)(Bm + (long long)br * K + k0 + c4 * 4);
            Bs[c4 * 4 + 0][rw] = b.x; Bs[c4 * 4 + 1][rw] = b.y;
            Bs[c4 * 4 + 2][rw] = b.z; Bs[c4 * 4 + 3][rw] = b.w;
        }
        __syncthreads();
#pragma unroll
        for (int kk = 0; kk < BK; kk++) {
            float4 a0 = *(const float4*)&As[kk][tm * 8];
            float4 a1 = *(const float4*)&As[kk][tm * 8 + 4];
            float4 b0 = *(const float4*)&Bs[kk][tn * 8];
            float4 b1 = *(const float4*)&Bs[kk][tn * 8 + 4];
            float av[8] = {a0.x, a0.y, a0.z, a0.w, a1.x, a1.y, a1.z, a1.w};
            float bv[8] = {b0.x, b0.y, b0.z, b0.w, b1.x, b1.y, b1.z, b1.w};
#pragma unroll
            for (int i = 0; i < 8; i++)
#pragma unroll
                for (int j = 0; j < 8; j++) acc[i][j] += av[i] * bv[j];
        }
        __syncthreads();
    }

    float bsum[8];
#pragma unroll
    for (int j = 0; j < 8; j++) {
        int n = n0 + tn * 8 + j;
        float bb = 0.f;
        if (n < N) {
            if (bias1) bb += bias1[n];
            if (bias2) bb += bias2[n];
        }
        bsum[j] = bb;
    }
#pragma unroll
    for (int i = 0; i < 8; i++) {
        int m = m0 + tm * 8 + i;
        if (m < M) {
#pragma unroll
            for (int j = 0; j < 8; j++) {
                int n = n0 + tn * 8 + j;
                if (n < N) C[(long long)m * N + n] = acc[i][j] + bsum[j];
            }
        }
    }
}

// ---------------- w_j and denom ----------------
__global__ __launch_bounds__(256) void k_simwj(
        const int* __restrict__ map, const int* __restrict__ length, const int* __restrict__ uid,
        const float* __restrict__ td_, const float* __restrict__ gd_,
        const float* __restrict__ encw, const float* __restrict__ ewu,
        float* __restrict__ wj, float* __restrict__ denom) {
    int b = blockIdx.x;
    __shared__ float up[H_];
    __shared__ float wjl[S_];
    int tid = threadIdx.x;
    int u = uid[b];
    up[tid] = ewu[(long long)u * H_ + tid];
    __syncthreads();
    int wv = tid >> 6, lane = tid & 63;
    int len = length[b];
    for (int s = wv; s < S_; s += 4) {
        int mi = map[b * S_ + s];
        float4 x = ((const float4*)(encw + (long long)mi * H_))[lane];
        float4 uu = *(const float4*)&up[lane * 4];
        float dx = uu.x - x.x, dy = uu.y - x.y, dz = uu.z - x.z, dw = uu.w - x.w;
        float d2 = dx * dx + dy * dy + dz * dz + dw * dw;
#pragma unroll
        for (int off = 32; off; off >>= 1) d2 += __shfl_xor(d2, off, 64);
        if (lane == 0) {
            float nrm = sqrtf(d2);
            float sim = expf(-nrm);
            float td = td_[b * S_ + s], gd = gd_[b * S_ + s];
            float aj = (cosf(td * 7.27220521664304e-05f) + 1.0f) * 0.5f *
                       expf(-td * 1.1574074074074073e-06f);
            float bj = expf(-gd * 1000.0f);
            float w = (aj * bj + 1e-10f) * sim;
            if (s >= len) w = 0.f;
            wjl[s] = w;
            wj[b * S_ + s] = w;
        }
    }
    __syncthreads();
    if (tid < 64) {
        float v = (tid < S_) ? wjl[tid] : 0.f;
        if (tid + 64 < S_) v += wjl[tid + 64];
#pragma unroll
        for (int off = 32; off; off >>= 1) v += __shfl_xor(v, off, 64);
        if (tid == 0) denom[b] = v;
    }
}

// ---------------- RNN: 4 batch rows per 1024-thread block, W_hh in registers ----------------
__global__ __launch_bounds__(1024) void k_rnn(
        const float* __restrict__ EWW, const float* __restrict__ Whh,
        const int* __restrict__ map, const float* __restrict__ wj,
        const float* __restrict__ h0g, float* __restrict__ out_acc) {
    __shared__ float hsh[4][H_];
    __shared__ float part[4][4][H_];
    __shared__ float wjs[4][S_];
    __shared__ int maps[4][S_];
    int tid = threadIdx.x;
    int q = tid >> 8, j = tid & 255;
    int b0 = blockIdx.x * 4;

    float wr[64];
    const float* wsrc = Whh + j * H_ + q * 64;
#pragma unroll
    for (int i = 0; i < 16; i++) {
        float4 t = *(const float4*)(wsrc + i * 4);
        wr[i * 4 + 0] = t.x; wr[i * 4 + 1] = t.y; wr[i * 4 + 2] = t.z; wr[i * 4 + 3] = t.w;
    }
    hsh[q][j] = h0g[(long long)(b0 + q) * H_ + j];
    if (tid < 4 * S_) {
        int r = tid / S_, s = tid % S_;
        wjs[r][s] = wj[(b0 + r) * S_ + s];
        maps[r][s] = map[(b0 + r) * S_ + s];
    }
    float accv = 0.f;
    __syncthreads();

    for (int s = 0; s < S_; s++) {
        float xwv = EWW[(long long)maps[q][s] * H_ + j];  // bias folded in
#pragma unroll
        for (int r = 0; r < 4; r++) {
            float p = 0.f;
#pragma unroll
            for (int k4 = 0; k4 < 16; k4++) {
                float4 hv = *(const float4*)&hsh[r][(q << 6) + k4 * 4];
                p += wr[k4 * 4 + 0] * hv.x + wr[k4 * 4 + 1] * hv.y +
                     wr[k4 * 4 + 2] * hv.z + wr[k4 * 4 + 3] * hv.w;
            }
            part[r][q][j] = p;
        }
        __syncthreads();
        float tot = part[q][0][j] + part[q][1][j] + part[q][2][j] + part[q][3][j] + xwv;
        float hn = tanhf(tot);
        hsh[q][j] = hn;
        accv += wjs[q][s] * hn;
        __syncthreads();
    }
    out_acc[(long long)(b0 + q) * H_ + j] = accv;
}

// ---------------- feature build: [out_w, p_u, out_w2] ----------------
__global__ __launch_bounds__(256) void k_feat(
        const float* __restrict__ out_acc, const float* __restrict__ denom,
        const int* __restrict__ uid, const float* __restrict__ user_emb,
        const int* __restrict__ seq, const float* __restrict__ wj,
        const float* __restrict__ emb2, float* __restrict__ feat) {
    int b = blockIdx.x, j = threadIdx.x;
    __shared__ float wjl[S_];
    __shared__ int sq[S_];
    if (j < S_) {
        wjl[j] = wj[b * S_ + j];
        sq[j] = seq[b * S_ + j];
    }
    __syncthreads();
    float inv = 1.f / denom[b];
    feat[(long long)b * 768 + j] = out_acc[(long long)b * H_ + j] * inv;
    feat[(long long)b * 768 + 256 + j] = user_emb[(long long)uid[b] * H_ + j];
    float a2 = 0.f;
    for (int s = 0; s < S_; s++) a2 += wjl[s] * emb2[(long long)sq[s] * H_ + j];
    feat[(long long)b * 768 + 512 + j] = a2 * inv;
}

extern "C" void kernel_launch(void* const* d_in, const int* in_sizes, int n_in,
                              void* d_out, int out_size, void* d_ws, size_t ws_size,
                              hipStream_t stream) {
    const int*   full_seq     = (const int*)d_in[0];
    const int*   full_seq_map = (const int*)d_in[1];
    const int*   length       = (const int*)d_in[2];
    const int*   user_id      = (const int*)d_in[3];
    const float* time_delta   = (const float*)d_in[4];
    const float* geo_delta    = (const float*)d_in[5];
    const float* enc_emb      = (const float*)d_in[6];
    const float* user_emb     = (const float*)d_in[7];
    const float* emb2         = (const float*)d_in[8];
    const int*   row_loc      = (const int*)d_in[9];
    const int*   col_loc      = (const int*)d_in[10];
    const float* vals_loc     = (const float*)d_in[11];
    const int*   row_usr      = (const int*)d_in[12];
    const int*   col_usr      = (const int*)d_in[13];
    const float* vals_usr     = (const float*)d_in[14];
    const float* W_ih         = (const float*)d_in[15];
    const float* W_hh         = (const float*)d_in[16];
    const float* b_ih         = (const float*)d_in[17];
    const float* b_hh         = (const float*)d_in[18];
    const float* W1           = (const float*)d_in[19];
    const float* b1           = (const float*)d_in[20];
    const float* h0g          = (const float*)d_in[21];
    float* out = (float*)d_out;

    float* ws = (float*)d_ws;
    size_t o = 0;
    float* encw  = ws + o; o += (size_t)L_ * H_;
    float* ewu   = ws + o; o += (size_t)U_ * H_;
    int*   flags = (int*)(ws + o); o += U_;
    size_t zero_elems = o;                 // zero everything up to here
    float* EWW   = ws + o; o += (size_t)L_ * H_;
    float* wj    = ws + o; o += (size_t)B_ * S_;
    float* denom = ws + o; o += B_;
    float* oacc  = ws + o; o += (size_t)B_ * H_;
    float* feat  = ws + o; o += (size_t)B_ * 3 * H_;

    hipMemsetAsync(d_ws, 0, zero_elems * sizeof(float), stream);
    k_mark<<<(B_ + 255) / 256, 256, 0, stream>>>(user_id, flags);
    k_scatter<<<(EL_ * 32 + 255) / 256, 256, 0, stream>>>(
        row_loc, col_loc, vals_loc, enc_emb, encw, nullptr, EL_);
    k_scatter<<<(EU_ * 32 + 255) / 256, 256, 0, stream>>>(
        row_usr, col_usr, vals_usr, enc_emb, ewu, flags, EU_);
    // EWW = encw @ W_ih^T + (b_ih + b_hh)
    k_gemm<<<dim3((L_ + BM - 1) / BM, (H_ + BN - 1) / BN), 256, 0, stream>>>(
        encw, W_ih, b_ih, b_hh, EWW, L_, H_, H_);
    k_simwj<<<B_, 256, 0, stream>>>(full_seq_map, length, user_id, time_delta,
                                    geo_delta, encw, ewu, wj, denom);
    k_rnn<<<B_ / 4, 1024, 0, stream>>>(EWW, W_hh, full_seq_map, wj, h0g, oacc);
    k_feat<<<B_, 256, 0, stream>>>(oacc, denom, user_id, user_emb, full_seq, wj, emb2, feat);
    // out = feat @ W1^T + b1   (x = m-tiles fastest so consecutive blocks share the W1 tile in L2)
    k_gemm<<<dim3((B_ + BM - 1) / BM, (L_ + BN - 1) / BN), 256, 0, stream>>>(
        feat, W1, b1, nullptr, out, B_, L_, 3 * H_);
}

// Round 2
// 1325.735 us; speedup vs baseline: 3.5220x; 3.5220x over previous
//
#include <hip/hip_runtime.h>
#include <math.h>

#define B_  1024
#define S_  100
#define H_  256
#define L_  20000
#define U_  20000
#define EL_ 500000
#define EU_ 400000

// ---------------- flags for needed user rows ----------------
__global__ void k_mark(const int* __restrict__ uid, int* __restrict__ flags) {
    int i = blockIdx.x * blockDim.x + threadIdx.x;
    if (i < B_) flags[uid[i]] = 1;
}

// ---------------- CSR build: histogram ----------------
__global__ void k_hist(const int* __restrict__ row, int* __restrict__ cnt, int nE) {
    int e = blockIdx.x * blockDim.x + threadIdx.x;
    if (e < nE) atomicAdd(&cnt[row[e]], 1);
}

// ---------------- CSR build: single-block exclusive scan over L_ entries ----------------
__global__ __launch_bounds__(1024) void k_scan(const int* __restrict__ cnt,
                                               int* __restrict__ offs,
                                               int* __restrict__ cursor) {
    __shared__ int wsum[16];
    __shared__ int carry_s;
    int tid = threadIdx.x;
    int lane = tid & 63, wv = tid >> 6;
    if (tid == 0) carry_s = 0;
    __syncthreads();
    for (int base = 0; base < L_; base += 1024) {
        int v = (base + tid < L_) ? cnt[base + tid] : 0;
        int x = v;
#pragma unroll
        for (int off = 1; off < 64; off <<= 1) {
            int y = __shfl_up(x, off, 64);
            if (lane >= off) x += y;
        }
        if (lane == 63) wsum[wv] = x;
        __syncthreads();
        if (wv == 0) {
            int s = (lane < 16) ? wsum[lane] : 0;
#pragma unroll
            for (int off = 1; off < 16; off <<= 1) {
                int y = __shfl_up(s, off, 64);
                if (lane >= off) s += y;
            }
            if (lane < 16) wsum[lane] = s;
        }
        __syncthreads();
        int excl = x - v + (wv ? wsum[wv - 1] : 0) + carry_s;
        if (base + tid < L_) { offs[base + tid] = excl; cursor[base + tid] = excl; }
        __syncthreads();                       // all reads of wsum/carry done
        if (tid == 0) carry_s += wsum[15];
        __syncthreads();                       // carry updated before next chunk
    }
    if (tid == 0) offs[L_] = carry_s;
}

// ---------------- CSR build: place edges ----------------
__global__ void k_place(const int* __restrict__ row, const int* __restrict__ col,
                        const float* __restrict__ vals, int* __restrict__ cursor,
                        int* __restrict__ col_s, float* __restrict__ val_s, int nE) {
    int e = blockIdx.x * blockDim.x + threadIdx.x;
    if (e >= nE) return;
    int pos = atomicAdd(&cursor[row[e]], 1);
    col_s[pos] = col[e];
    val_s[pos] = vals[e];
}

// ---------------- gather-accumulate: one block per row, no atomics ----------------
__global__ __launch_bounds__(256) void k_gather(const int* __restrict__ offs,
                                                const int* __restrict__ col_s,
                                                const float* __restrict__ val_s,
                                                const float* __restrict__ emb,
                                                float* __restrict__ out) {
    int r = blockIdx.x;
    int tid = threadIdx.x;
    int lo = offs[r], hi = offs[r + 1];
    float acc = 0.f;
    int i = lo;
    for (; i + 1 < hi; i += 2) {
        int c0 = col_s[i], c1 = col_s[i + 1];
        float v0 = val_s[i], v1 = val_s[i + 1];
        float e0 = emb[(long long)c0 * H_ + tid];
        float e1 = emb[(long long)c1 * H_ + tid];
        acc += v0 * e0 + v1 * e1;
    }
    if (i < hi) acc += val_s[i] * emb[(long long)col_s[i] * H_ + tid];
    out[(long long)r * H_ + tid] = acc;
}

// ---------------- COO atomic scatter (user graph, flags-filtered) ----------------
__global__ void k_scatter(const int* __restrict__ row, const int* __restrict__ col,
                          const float* __restrict__ vals, const float* __restrict__ emb,
                          float* __restrict__ out, const int* __restrict__ flags, int nE) {
    long long tid = (long long)blockIdx.x * blockDim.x + threadIdx.x;
    int e = (int)(tid >> 5);
    if (e >= nE) return;
    int r = row[e];
    if (flags && !flags[r]) return;
    int part = (int)(tid & 31);
    int c = col[e];
    float v = vals[e];
    int h0 = part * 8;
    const float4* s4 = (const float4*)(emb + (long long)c * H_ + h0);
    float4 x0 = s4[0], x1 = s4[1];
    float* dst = out + (long long)r * H_ + h0;
    atomicAdd(dst + 0, v * x0.x); atomicAdd(dst + 1, v * x0.y);
    atomicAdd(dst + 2, v * x0.z); atomicAdd(dst + 3, v * x0.w);
    atomicAdd(dst + 4, v * x1.x); atomicAdd(dst + 5, v * x1.y);
    atomicAdd(dst + 6, v * x1.z); atomicAdd(dst + 7, v * x1.w);
}

// ---------------- generic f32 GEMM: C[m,n] = sum_k A[m,k]*Bm[n,k] + bias1[n] + bias2[n] ----------------
#define BM 128
#define BN 128
#define BK 16
#define PADW 132

__global__ __launch_bounds__(256) void k_gemm(
        const float* __restrict__ A, const float* __restrict__ Bm,
        const float* __restrict__ bias1, const float* __restrict__ bias2,
        float* __restrict__ C, int M, int N, int K) {
    __shared__ float As[BK][PADW];
    __shared__ float Bs[BK][PADW];
    int m0 = blockIdx.x * BM;
    int n0 = blockIdx.y * BN;
    int tid = threadIdx.x;
    int tn = tid & 15, tm = tid >> 4;

    float acc[8][8];
#pragma unroll
    for (int i = 0; i < 8; i++)
#pragma unroll
        for (int j = 0; j < 8; j++) acc[i][j] = 0.f;

    for (int k0 = 0; k0 < K; k0 += BK) {
#pragma unroll
        for (int h = 0; h < 2; h++) {
            int v = tid + h * 256;
            int rw = v >> 2, c4 = v & 3;
            int ar = m0 + rw; if (ar > M - 1) ar = M - 1;
            float4 a = *(const float4*)(A + (long long)ar * K + k0 + c4 * 4);
            As[c4 * 4 + 0][rw] = a.x; As[c4 * 4 + 1][rw] = a.y;
            As[c4 * 4 + 2][rw] = a.z; As[c4 * 4 + 3][rw] = a.w;
            int br = n0 + rw; if (br > N - 1) br = N - 1;
            float4 b = *(const float4*)(Bm + (long long)br * K + k0 + c4 * 4);
            Bs[c4 * 4 + 0][rw] = b.x; Bs[c4 * 4 + 1][rw] = b.y;
            Bs[c4 * 4 + 2][rw] = b.z; Bs[c4 * 4 + 3][rw] = b.w;
        }
        __syncthreads();
#pragma unroll
        for (int kk = 0; kk < BK; kk++) {
            float4 a0 = *(const float4*)&As[kk][tm * 8];
            float4 a1 = *(const float4*)&As[kk][tm * 8 + 4];
            float4 b0 = *(const float4*)&Bs[kk][tn * 8];
            float4 b1 = *(const float4*)&Bs[kk][tn * 8 + 4];
            float av[8] = {a0.x, a0.y, a0.z, a0.w, a1.x, a1.y, a1.z, a1.w};
            float bv[8] = {b0.x, b0.y, b0.z, b0.w, b1.x, b1.y, b1.z, b1.w};
#pragma unroll
            for (int i = 0; i < 8; i++)
#pragma unroll
                for (int j = 0; j < 8; j++) acc[i][j] += av[i] * bv[j];
        }
        __syncthreads();
    }

    float bsum[8];
#pragma unroll
    for (int j = 0; j < 8; j++) {
        int n = n0 + tn * 8 + j;
        float bb = 0.f;
        if (n < N) {
            if (bias1) bb += bias1[n];
            if (bias2) bb += bias2[n];
        }
        bsum[j] = bb;
    }
#pragma unroll
    for (int i = 0; i < 8; i++) {
        int m = m0 + tm * 8 + i;
        if (m < M) {
#pragma unroll
            for (int j = 0; j < 8; j++) {
                int n = n0 + tn * 8 + j;
                if (n < N) C[(long long)m * N + n] = acc[i][j] + bsum[j];
            }
        }
    }
}

// ---------------- w_j and denom ----------------
__global__ __launch_bounds__(256) void k_simwj(
        const int* __restrict__ map, const int* __restrict__ length, const int* __restrict__ uid,
        const float* __restrict__ td_, const float* __restrict__ gd_,
        const float* __restrict__ encw, const float* __restrict__ ewu,
        float* __restrict__ wj, float* __restrict__ denom) {
    int b = blockIdx.x;
    __shared__ float up[H_];
    __shared__ float wjl[S_];
    int tid = threadIdx.x;
    int u = uid[b];
    up[tid] = ewu[(long long)u * H_ + tid];
    __syncthreads();
    int wv = tid >> 6, lane = tid & 63;
    int len = length[b];
    for (int s = wv; s < S_; s += 4) {
        int mi = map[b * S_ + s];
        float4 x = ((const float4*)(encw + (long long)mi * H_))[lane];
        float4 uu = *(const float4*)&up[lane * 4];
        float dx = uu.x - x.x, dy = uu.y - x.y, dz = uu.z - x.z, dw = uu.w - x.w;
        float d2 = dx * dx + dy * dy + dz * dz + dw * dw;
#pragma unroll
        for (int off = 32; off; off >>= 1) d2 += __shfl_xor(d2, off, 64);
        if (lane == 0) {
            float nrm = sqrtf(d2);
            float sim = expf(-nrm);
            float td = td_[b * S_ + s], gd = gd_[b * S_ + s];
            float aj = (cosf(td * 7.27220521664304e-05f) + 1.0f) * 0.5f *
                       expf(-td * 1.1574074074074073e-06f);
            float bj = expf(-gd * 1000.0f);
            float w = (aj * bj + 1e-10f) * sim;
            if (s >= len) w = 0.f;
            wjl[s] = w;
            wj[b * S_ + s] = w;
        }
    }
    __syncthreads();
    if (tid < 64) {
        float v = (tid < S_) ? wjl[tid] : 0.f;
        if (tid + 64 < S_) v += wjl[tid + 64];
#pragma unroll
        for (int off = 32; off; off >>= 1) v += __shfl_xor(v, off, 64);
        if (tid == 0) denom[b] = v;
    }
}

// ---------------- RNN: 4 batch rows per 1024-thread block, W_hh in registers ----------------
__global__ __launch_bounds__(1024) void k_rnn(
        const float* __restrict__ EWW, const float* __restrict__ Whh,
        const int* __restrict__ map, const float* __restrict__ wj,
        const float* __restrict__ h0g, float* __restrict__ out_acc) {
    __shared__ float hsh[4][H_];
    __shared__ float part[4][4][H_];
    __shared__ float wjs[4][S_];
    __shared__ int maps[4][S_];
    int tid = threadIdx.x;
    int q = tid >> 8, j = tid & 255;
    int b0 = blockIdx.x * 4;

    float wr[64];
    const float* wsrc = Whh + j * H_ + q * 64;
#pragma unroll
    for (int i = 0; i < 16; i++) {
        float4 t = *(const float4*)(wsrc + i * 4);
        wr[i * 4 + 0] = t.x; wr[i * 4 + 1] = t.y; wr[i * 4 + 2] = t.z; wr[i * 4 + 3] = t.w;
    }
    hsh[q][j] = h0g[(long long)(b0 + q) * H_ + j];
    if (tid < 4 * S_) {
        int r = tid / S_, s = tid % S_;
        wjs[r][s] = wj[(b0 + r) * S_ + s];
        maps[r][s] = map[(b0 + r) * S_ + s];
    }
    float accv = 0.f;
    __syncthreads();

    for (int s = 0; s < S_; s++) {
        float xwv = EWW[(long long)maps[q][s] * H_ + j];  // bias folded in
#pragma unroll
        for (int r = 0; r < 4; r++) {
            float p = 0.f;
#pragma unroll
            for (int k4 = 0; k4 < 16; k4++) {
                float4 hv = *(const float4*)&hsh[r][(q << 6) + k4 * 4];
                p += wr[k4 * 4 + 0] * hv.x + wr[k4 * 4 + 1] * hv.y +
                     wr[k4 * 4 + 2] * hv.z + wr[k4 * 4 + 3] * hv.w;
            }
            part[r][q][j] = p;
        }
        __syncthreads();
        float tot = part[q][0][j] + part[q][1][j] + part[q][2][j] + part[q][3][j] + xwv;
        float hn = tanhf(tot);
        hsh[q][j] = hn;
        accv += wjs[q][s] * hn;
        __syncthreads();
    }
    out_acc[(long long)(b0 + q) * H_ + j] = accv;
}

// ---------------- feature build: [out_w, p_u, out_w2] ----------------
__global__ __launch_bounds__(256) void k_feat(
        const float* __restrict__ out_acc, const float* __restrict__ denom,
        const int* __restrict__ uid, const float* __restrict__ user_emb,
        const int* __restrict__ seq, const float* __restrict__ wj,
        const float* __restrict__ emb2, float* __restrict__ feat) {
    int b = blockIdx.x, j = threadIdx.x;
    __shared__ float wjl[S_];
    __shared__ int sq[S_];
    if (j < S_) {
        wjl[j] = wj[b * S_ + j];
        sq[j] = seq[b * S_ + j];
    }
    __syncthreads();
    float inv = 1.f / denom[b];
    feat[(long long)b * 768 + j] = out_acc[(long long)b * H_ + j] * inv;
    feat[(long long)b * 768 + 256 + j] = user_emb[(long long)uid[b] * H_ + j];
    float a2 = 0.f;
    for (int s = 0; s < S_; s++) a2 += wjl[s] * emb2[(long long)sq[s] * H_ + j];
    feat[(long long)b * 768 + 512 + j] = a2 * inv;
}

extern "C" void kernel_launch(void* const* d_in, const int* in_sizes, int n_in,
                              void* d_out, int out_size, void* d_ws, size_t ws_size,
                              hipStream_t stream) {
    const int*   full_seq     = (const int*)d_in[0];
    const int*   full_seq_map = (const int*)d_in[1];
    const int*   length       = (const int*)d_in[2];
    const int*   user_id      = (const int*)d_in[3];
    const float* time_delta   = (const float*)d_in[4];
    const float* geo_delta    = (const float*)d_in[5];
    const float* enc_emb      = (const float*)d_in[6];
    const float* user_emb     = (const float*)d_in[7];
    const float* emb2         = (const float*)d_in[8];
    const int*   row_loc      = (const int*)d_in[9];
    const int*   col_loc      = (const int*)d_in[10];
    const float* vals_loc     = (const float*)d_in[11];
    const int*   row_usr      = (const int*)d_in[12];
    const int*   col_usr      = (const int*)d_in[13];
    const float* vals_usr     = (const float*)d_in[14];
    const float* W_ih         = (const float*)d_in[15];
    const float* W_hh         = (const float*)d_in[16];
    const float* b_ih         = (const float*)d_in[17];
    const float* b_hh         = (const float*)d_in[18];
    const float* W1           = (const float*)d_in[19];
    const float* b1           = (const float*)d_in[20];
    const float* h0g          = (const float*)d_in[21];
    float* out = (float*)d_out;

    float* ws = (float*)d_ws;
    size_t o = 0;
    float* ewu   = ws + o; o += (size_t)U_ * H_;
    int*   flags = (int*)(ws + o); o += U_;
    size_t zero_elems = o;                 // zero ewu + flags
    float* encw  = ws + o; o += (size_t)L_ * H_;
    float* EWW   = ws + o; o += (size_t)L_ * H_;
    // ---- region written only AFTER gather completes; aliased by CSR arrays ----
    size_t late_base = o;
    float* wj    = ws + o; o += (size_t)B_ * S_;
    float* denom = ws + o; o += B_;
    float* oacc  = ws + o; o += (size_t)B_ * H_;
    float* feat  = ws + o; o += (size_t)B_ * 3 * H_;
    // CSR arrays alias [late_base, late_base + 1,152,000) — need 1,060,003
    size_t a = late_base;
    int*   cnt    = (int*)(ws + a); a += L_ + 1;
    int*   offs   = (int*)(ws + a); a += L_ + 1;
    int*   cursor = (int*)(ws + a); a += L_ + 1;
    int*   col_s  = (int*)(ws + a); a += EL_;
    float* val_s  = ws + a;         a += EL_;

    hipMemsetAsync(d_ws, 0, zero_elems * sizeof(float), stream);
    hipMemsetAsync(cnt, 0, (L_ + 1) * sizeof(int), stream);
    k_mark<<<(B_ + 255) / 256, 256, 0, stream>>>(user_id, flags);

    // ---- loc-loc graph: CSR build + deterministic gather (replaces 128M f32 atomics) ----
    k_hist<<<(EL_ + 255) / 256, 256, 0, stream>>>(row_loc, cnt, EL_);
    k_scan<<<1, 1024, 0, stream>>>(cnt, offs, cursor);
    k_place<<<(EL_ + 255) / 256, 256, 0, stream>>>(row_loc, col_loc, vals_loc,
                                                   cursor, col_s, val_s, EL_);
    k_gather<<<L_, 256, 0, stream>>>(offs, col_s, val_s, enc_emb, encw);

    // ---- user-loc graph: flags-filtered atomic scatter (~5% of edges) ----
    k_scatter<<<(EU_ * 32 + 255) / 256, 256, 0, stream>>>(
        row_usr, col_usr, vals_usr, enc_emb, ewu, flags, EU_);

    // EWW = encw @ W_ih^T + (b_ih + b_hh)
    k_gemm<<<dim3((L_ + BM - 1) / BM, (H_ + BN - 1) / BN), 256, 0, stream>>>(
        encw, W_ih, b_ih, b_hh, EWW, L_, H_, H_);
    k_simwj<<<B_, 256, 0, stream>>>(full_seq_map, length, user_id, time_delta,
                                    geo_delta, encw, ewu, wj, denom);
    k_rnn<<<B_ / 4, 1024, 0, stream>>>(EWW, W_hh, full_seq_map, wj, h0g, oacc);
    k_feat<<<B_, 256, 0, stream>>>(oacc, denom, user_id, user_emb, full_seq, wj, emb2, feat);
    // out = feat @ W1^T + b1
    k_gemm<<<dim3((B_ + BM - 1) / BM, (L_ + BN - 1) / BN), 256, 0, stream>>>(
        feat, W1, b1, nullptr, out, B_, L_, 3 * H_);
}

// Round 3
// 1015.566 us; speedup vs baseline: 4.5977x; 1.3054x over previous
//
#include <hip/hip_runtime.h>
#include <math.h>

#define B_  1024
#define S_  100
#define H_  256
#define L_  20000
#define U_  20000
#define EL_ 500000
#define EU_ 400000

typedef __bf16 bf16x8 __attribute__((ext_vector_type(8)));
typedef __bf16 bf16x4 __attribute__((ext_vector_type(4)));
typedef float  f32x4  __attribute__((ext_vector_type(4)));

// ---------------- flags for needed user rows ----------------
__global__ void k_mark(const int* __restrict__ uid, int* __restrict__ flags) {
    int i = blockIdx.x * blockDim.x + threadIdx.x;
    if (i < B_) flags[uid[i]] = 1;
}

// ---------------- CSR build: histogram ----------------
__global__ void k_hist(const int* __restrict__ row, int* __restrict__ cnt, int nE) {
    int e = blockIdx.x * blockDim.x + threadIdx.x;
    if (e < nE) atomicAdd(&cnt[row[e]], 1);
}

// ---------------- CSR build: single-block exclusive scan ----------------
__global__ __launch_bounds__(1024) void k_scan(const int* __restrict__ cnt,
                                               int* __restrict__ offs,
                                               int* __restrict__ cursor) {
    __shared__ int wsum[16];
    __shared__ int carry_s;
    int tid = threadIdx.x;
    int lane = tid & 63, wv = tid >> 6;
    if (tid == 0) carry_s = 0;
    __syncthreads();
    for (int base = 0; base < L_; base += 1024) {
        int v = (base + tid < L_) ? cnt[base + tid] : 0;
        int x = v;
#pragma unroll
        for (int off = 1; off < 64; off <<= 1) {
            int y = __shfl_up(x, off, 64);
            if (lane >= off) x += y;
        }
        if (lane == 63) wsum[wv] = x;
        __syncthreads();
        if (wv == 0) {
            int s = (lane < 16) ? wsum[lane] : 0;
#pragma unroll
            for (int off = 1; off < 16; off <<= 1) {
                int y = __shfl_up(s, off, 64);
                if (lane >= off) s += y;
            }
            if (lane < 16) wsum[lane] = s;
        }
        __syncthreads();
        int excl = x - v + (wv ? wsum[wv - 1] : 0) + carry_s;
        if (base + tid < L_) { offs[base + tid] = excl; cursor[base + tid] = excl; }
        __syncthreads();
        if (tid == 0) carry_s += wsum[15];
        __syncthreads();
    }
    if (tid == 0) offs[L_] = carry_s;
}

// ---------------- CSR build: place edges ----------------
__global__ void k_place(const int* __restrict__ row, const int* __restrict__ col,
                        const float* __restrict__ vals, int* __restrict__ cursor,
                        int* __restrict__ col_s, float* __restrict__ val_s, int nE) {
    int e = blockIdx.x * blockDim.x + threadIdx.x;
    if (e >= nE) return;
    int pos = atomicAdd(&cursor[row[e]], 1);
    col_s[pos] = col[e];
    val_s[pos] = vals[e];
}

// ---------------- gather-accumulate: one block per row, no atomics ----------------
__global__ __launch_bounds__(256) void k_gather(const int* __restrict__ offs,
                                                const int* __restrict__ col_s,
                                                const float* __restrict__ val_s,
                                                const float* __restrict__ emb,
                                                float* __restrict__ out) {
    int r = blockIdx.x;
    int tid = threadIdx.x;
    int lo = offs[r], hi = offs[r + 1];
    float acc = 0.f;
    int i = lo;
    for (; i + 1 < hi; i += 2) {
        int c0 = col_s[i], c1 = col_s[i + 1];
        float v0 = val_s[i], v1 = val_s[i + 1];
        float e0 = emb[(long long)c0 * H_ + tid];
        float e1 = emb[(long long)c1 * H_ + tid];
        acc += v0 * e0 + v1 * e1;
    }
    if (i < hi) acc += val_s[i] * emb[(long long)col_s[i] * H_ + tid];
    out[(long long)r * H_ + tid] = acc;
}

// ---------------- COO atomic scatter (user graph, flags-filtered) ----------------
__global__ void k_scatter(const int* __restrict__ row, const int* __restrict__ col,
                          const float* __restrict__ vals, const float* __restrict__ emb,
                          float* __restrict__ out, const int* __restrict__ flags, int nE) {
    long long tid = (long long)blockIdx.x * blockDim.x + threadIdx.x;
    int e = (int)(tid >> 5);
    if (e >= nE) return;
    int r = row[e];
    if (flags && !flags[r]) return;
    int part = (int)(tid & 31);
    int c = col[e];
    float v = vals[e];
    int h0 = part * 8;
    const float4* s4 = (const float4*)(emb + (long long)c * H_ + h0);
    float4 x0 = s4[0], x1 = s4[1];
    float* dst = out + (long long)r * H_ + h0;
    atomicAdd(dst + 0, v * x0.x); atomicAdd(dst + 1, v * x0.y);
    atomicAdd(dst + 2, v * x0.z); atomicAdd(dst + 3, v * x0.w);
    atomicAdd(dst + 4, v * x1.x); atomicAdd(dst + 5, v * x1.y);
    atomicAdd(dst + 6, v * x1.z); atomicAdd(dst + 7, v * x1.w);
}

// ---------------- f32 GEMM (EWW only): C = A @ B^T + bias ----------------
#define BM 128
#define BN 128
#define BK 16
#define PADW 132

__global__ __launch_bounds__(256) void k_gemm(
        const float* __restrict__ A, const float* __restrict__ Bm,
        const float* __restrict__ bias1, const float* __restrict__ bias2,
        float* __restrict__ C, int M, int N, int K) {
    __shared__ float As[BK][PADW];
    __shared__ float Bs[BK][PADW];
    int m0 = blockIdx.x * BM;
    int n0 = blockIdx.y * BN;
    int tid = threadIdx.x;
    int tn = tid & 15, tm = tid >> 4;

    float acc[8][8];
#pragma unroll
    for (int i = 0; i < 8; i++)
#pragma unroll
        for (int j = 0; j < 8; j++) acc[i][j] = 0.f;

    for (int k0 = 0; k0 < K; k0 += BK) {
#pragma unroll
        for (int h = 0; h < 2; h++) {
            int v = tid + h * 256;
            int rw = v >> 2, c4 = v & 3;
            int ar = m0 + rw; if (ar > M - 1) ar = M - 1;
            float4 a = *(const float4*)(A + (long long)ar * K + k0 + c4 * 4);
            As[c4 * 4 + 0][rw] = a.x; As[c4 * 4 + 1][rw] = a.y;
            As[c4 * 4 + 2][rw] = a.z; As[c4 * 4 + 3][rw] = a.w;
            int br = n0 + rw; if (br > N - 1) br = N - 1;
            float4 b = *(const float4*)(Bm + (long long)br * K + k0 + c4 * 4);
            Bs[c4 * 4 + 0][rw] = b.x; Bs[c4 * 4 + 1][rw] = b.y;
            Bs[c4 * 4 + 2][rw] = b.z; Bs[c4 * 4 + 3][rw] = b.w;
        }
        __syncthreads();
#pragma unroll
        for (int kk = 0; kk < BK; kk++) {
            float4 a0 = *(const float4*)&As[kk][tm * 8];
            float4 a1 = *(const float4*)&As[kk][tm * 8 + 4];
            float4 b0 = *(const float4*)&Bs[kk][tn * 8];
            float4 b1 = *(const float4*)&Bs[kk][tn * 8 + 4];
            float av[8] = {a0.x, a0.y, a0.z, a0.w, a1.x, a1.y, a1.z, a1.w};
            float bv[8] = {b0.x, b0.y, b0.z, b0.w, b1.x, b1.y, b1.z, b1.w};
#pragma unroll
            for (int i = 0; i < 8; i++)
#pragma unroll
                for (int j = 0; j < 8; j++) acc[i][j] += av[i] * bv[j];
        }
        __syncthreads();
    }

    float bsum[8];
#pragma unroll
    for (int j = 0; j < 8; j++) {
        int n = n0 + tn * 8 + j;
        float bb = 0.f;
        if (n < N) {
            if (bias1) bb += bias1[n];
            if (bias2) bb += bias2[n];
        }
        bsum[j] = bb;
    }
#pragma unroll
    for (int i = 0; i < 8; i++) {
        int m = m0 + tm * 8 + i;
        if (m < M) {
#pragma unroll
            for (int j = 0; j < 8; j++) {
                int n = n0 + tn * 8 + j;
                if (n < N) C[(long long)m * N + n] = acc[i][j] + bsum[j];
            }
        }
    }
}

// ---------------- f32 -> bf16 conversion (vectorized) ----------------
__global__ __launch_bounds__(256) void k_cvt(const float4* __restrict__ src,
                                             bf16x4* __restrict__ dst, int n4) {
    int i = blockIdx.x * blockDim.x + threadIdx.x;
    if (i >= n4) return;
    float4 v = src[i];
    bf16x4 o;
    o[0] = (__bf16)v.x; o[1] = (__bf16)v.y; o[2] = (__bf16)v.z; o[3] = (__bf16)v.w;
    dst[i] = o;
}

// ---------------- bf16 MFMA GEMM: C[m,n] = A[m,:] . Bw[n,:] + bias[n] ----------------
// 128x128 tile, BK=32, 4 waves each 64x64. global_load_lds staging with XOR
// chunk swizzle (chunk = row*4 + (q ^ ((row>>1)&3))) -> 2-way LDS aliasing (free).
__global__ __launch_bounds__(256) void k_gemm_bf16(
        const __bf16* __restrict__ A, const __bf16* __restrict__ Bw,
        const float* __restrict__ bias, float* __restrict__ C,
        int M, int N, int K) {
    __shared__ __bf16 Asl[128 * 32];
    __shared__ __bf16 Bsl[128 * 32];
    int tid = threadIdx.x;
    int lane = tid & 63, w = tid >> 6;
    int wm = w >> 1, wn = w & 1;
    int m0 = blockIdx.x * 128, n0 = blockIdx.y * 128;

    f32x4 acc[4][4];
#pragma unroll
    for (int i = 0; i < 4; i++)
#pragma unroll
        for (int j = 0; j < 4; j++) acc[i][j] = (f32x4){0.f, 0.f, 0.f, 0.f};

    int fm = lane & 15, fq = lane >> 4;

    for (int k0 = 0; k0 < K; k0 += 32) {
        // stage A and B tiles: 2 rounds x 4 waves x 64 lanes x 16B each
#pragma unroll
        for (int h = 0; h < 2; h++) {
            int c = h * 256 + w * 64 + lane;       // chunk index 0..511
            int r = c >> 2, qsw = c & 3;
            int q = qsw ^ ((r >> 1) & 3);
            const __bf16* gA = A + (long long)(m0 + r) * K + k0 + q * 8;
            __builtin_amdgcn_global_load_lds(
                (const __attribute__((address_space(1))) void*)gA,
                (__attribute__((address_space(3))) void*)(Asl + (h * 256 + w * 64) * 8),
                16, 0, 0);
            int br = n0 + r; if (br > N - 1) br = N - 1;
            const __bf16* gB = Bw + (long long)br * K + k0 + q * 8;
            __builtin_amdgcn_global_load_lds(
                (const __attribute__((address_space(1))) void*)gB,
                (__attribute__((address_space(3))) void*)(Bsl + (h * 256 + w * 64) * 8),
                16, 0, 0);
        }
        __syncthreads();   // drains vmcnt -> staged data visible

        bf16x8 af[4], bfr[4];
#pragma unroll
        for (int mi = 0; mi < 4; mi++) {
            int r = wm * 64 + mi * 16 + fm;
            int ch = r * 4 + (fq ^ ((r >> 1) & 3));
            af[mi] = *(const bf16x8*)(Asl + ch * 8);
        }
#pragma unroll
        for (int ni = 0; ni < 4; ni++) {
            int r = wn * 64 + ni * 16 + fm;
            int ch = r * 4 + (fq ^ ((r >> 1) & 3));
            bfr[ni] = *(const bf16x8*)(Bsl + ch * 8);
        }
#pragma unroll
        for (int mi = 0; mi < 4; mi++)
#pragma unroll
            for (int ni = 0; ni < 4; ni++)
                acc[mi][ni] = __builtin_amdgcn_mfma_f32_16x16x32_bf16(
                    af[mi], bfr[ni], acc[mi][ni], 0, 0, 0);
        __syncthreads();   // all LDS reads done before next stage overwrites
    }

    // epilogue: C/D layout col = lane&15, row = (lane>>4)*4 + reg
#pragma unroll
    for (int ni = 0; ni < 4; ni++) {
        int col = n0 + wn * 64 + ni * 16 + fm;
        if (col >= N) continue;
        float bb = bias[col];
#pragma unroll
        for (int mi = 0; mi < 4; mi++) {
            int row = m0 + wm * 64 + mi * 16 + fq * 4;
#pragma unroll
            for (int r = 0; r < 4; r++)
                C[(long long)(row + r) * N + col] = acc[mi][ni][r] + bb;
        }
    }
}

// ---------------- w_j and denom ----------------
__global__ __launch_bounds__(256) void k_simwj(
        const int* __restrict__ map, const int* __restrict__ length, const int* __restrict__ uid,
        const float* __restrict__ td_, const float* __restrict__ gd_,
        const float* __restrict__ encw, const float* __restrict__ ewu,
        float* __restrict__ wj, float* __restrict__ denom) {
    int b = blockIdx.x;
    __shared__ float up[H_];
    __shared__ float wjl[S_];
    int tid = threadIdx.x;
    int u = uid[b];
    up[tid] = ewu[(long long)u * H_ + tid];
    __syncthreads();
    int wv = tid >> 6, lane = tid & 63;
    int len = length[b];
    for (int s = wv; s < S_; s += 4) {
        int mi = map[b * S_ + s];
        float4 x = ((const float4*)(encw + (long long)mi * H_))[lane];
        float4 uu = *(const float4*)&up[lane * 4];
        float dx = uu.x - x.x, dy = uu.y - x.y, dz = uu.z - x.z, dw = uu.w - x.w;
        float d2 = dx * dx + dy * dy + dz * dz + dw * dw;
#pragma unroll
        for (int off = 32; off; off >>= 1) d2 += __shfl_xor(d2, off, 64);
        if (lane == 0) {
            float nrm = sqrtf(d2);
            float sim = expf(-nrm);
            float td = td_[b * S_ + s], gd = gd_[b * S_ + s];
            float aj = (cosf(td * 7.27220521664304e-05f) + 1.0f) * 0.5f *
                       expf(-td * 1.1574074074074073e-06f);
            float bj = expf(-gd * 1000.0f);
            float w = (aj * bj + 1e-10f) * sim;
            if (s >= len) w = 0.f;
            wjl[s] = w;
            wj[b * S_ + s] = w;
        }
    }
    __syncthreads();
    if (tid < 64) {
        float v = (tid < S_) ? wjl[tid] : 0.f;
        if (tid + 64 < S_) v += wjl[tid + 64];
#pragma unroll
        for (int off = 32; off; off >>= 1) v += __shfl_xor(v, off, 64);
        if (tid == 0) denom[b] = v;
    }
}

// ---------------- RNN: 4 batch rows per 1024-thread block ----------------
__global__ __launch_bounds__(1024) void k_rnn(
        const float* __restrict__ EWW, const float* __restrict__ Whh,
        const int* __restrict__ map, const float* __restrict__ wj,
        const float* __restrict__ h0g, float* __restrict__ out_acc) {
    __shared__ float hsh[4][H_];
    __shared__ float part[4][4][H_];
    __shared__ float wjs[4][S_];
    __shared__ int maps[4][S_];
    int tid = threadIdx.x;
    int q = tid >> 8, j = tid & 255;
    int b0 = blockIdx.x * 4;

    float wr[64];
    const float* wsrc = Whh + j * H_ + q * 64;
#pragma unroll
    for (int i = 0; i < 16; i++) {
        float4 t = *(const float4*)(wsrc + i * 4);
        wr[i * 4 + 0] = t.x; wr[i * 4 + 1] = t.y; wr[i * 4 + 2] = t.z; wr[i * 4 + 3] = t.w;
    }
    hsh[q][j] = h0g[(long long)(b0 + q) * H_ + j];
    if (tid < 4 * S_) {
        int r = tid / S_, s = tid % S_;
        wjs[r][s] = wj[(b0 + r) * S_ + s];
        maps[r][s] = map[(b0 + r) * S_ + s];
    }
    float accv = 0.f;
    __syncthreads();

    for (int s = 0; s < S_; s++) {
        float xwv = EWW[(long long)maps[q][s] * H_ + j];
#pragma unroll
        for (int r = 0; r < 4; r++) {
            float p = 0.f;
#pragma unroll
            for (int k4 = 0; k4 < 16; k4++) {
                float4 hv = *(const float4*)&hsh[r][(q << 6) + k4 * 4];
                p += wr[k4 * 4 + 0] * hv.x + wr[k4 * 4 + 1] * hv.y +
                     wr[k4 * 4 + 2] * hv.z + wr[k4 * 4 + 3] * hv.w;
            }
            part[r][q][j] = p;
        }
        __syncthreads();
        float tot = part[q][0][j] + part[q][1][j] + part[q][2][j] + part[q][3][j] + xwv;
        float hn = tanhf(tot);
        hsh[q][j] = hn;
        accv += wjs[q][s] * hn;
        __syncthreads();
    }
    out_acc[(long long)(b0 + q) * H_ + j] = accv;
}

// ---------------- feature build: [out_w, p_u, out_w2] ----------------
__global__ __launch_bounds__(256) void k_feat(
        const float* __restrict__ out_acc, const float* __restrict__ denom,
        const int* __restrict__ uid, const float* __restrict__ user_emb,
        const int* __restrict__ seq, const float* __restrict__ wj,
        const float* __restrict__ emb2, float* __restrict__ feat) {
    int b = blockIdx.x, j = threadIdx.x;
    __shared__ float wjl[S_];
    __shared__ int sq[S_];
    if (j < S_) {
        wjl[j] = wj[b * S_ + j];
        sq[j] = seq[b * S_ + j];
    }
    __syncthreads();
    float inv = 1.f / denom[b];
    feat[(long long)b * 768 + j] = out_acc[(long long)b * H_ + j] * inv;
    feat[(long long)b * 768 + 256 + j] = user_emb[(long long)uid[b] * H_ + j];
    float a2 = 0.f;
    for (int s = 0; s < S_; s++) a2 += wjl[s] * emb2[(long long)sq[s] * H_ + j];
    feat[(long long)b * 768 + 512 + j] = a2 * inv;
}

extern "C" void kernel_launch(void* const* d_in, const int* in_sizes, int n_in,
                              void* d_out, int out_size, void* d_ws, size_t ws_size,
                              hipStream_t stream) {
    const int*   full_seq     = (const int*)d_in[0];
    const int*   full_seq_map = (const int*)d_in[1];
    const int*   length       = (const int*)d_in[2];
    const int*   user_id      = (const int*)d_in[3];
    const float* time_delta   = (const float*)d_in[4];
    const float* geo_delta    = (const float*)d_in[5];
    const float* enc_emb      = (const float*)d_in[6];
    const float* user_emb     = (const float*)d_in[7];
    const float* emb2         = (const float*)d_in[8];
    const int*   row_loc      = (const int*)d_in[9];
    const int*   col_loc      = (const int*)d_in[10];
    const float* vals_loc     = (const float*)d_in[11];
    const int*   row_usr      = (const int*)d_in[12];
    const int*   col_usr      = (const int*)d_in[13];
    const float* vals_usr     = (const float*)d_in[14];
    const float* W_ih         = (const float*)d_in[15];
    const float* W_hh         = (const float*)d_in[16];
    const float* b_ih         = (const float*)d_in[17];
    const float* b_hh         = (const float*)d_in[18];
    const float* W1           = (const float*)d_in[19];
    const float* b1           = (const float*)d_in[20];
    const float* h0g          = (const float*)d_in[21];
    float* out = (float*)d_out;

    float* ws = (float*)d_ws;
    size_t o = 0;
    float* ewu   = ws + o; o += (size_t)U_ * H_;            // [0, 5.12M)
    int*   flags = (int*)(ws + o); o += U_;
    size_t zero_elems = o;
    float* encw  = ws + o; o += (size_t)L_ * H_;            // [5.14M, 10.26M)
    float* EWW   = ws + o; o += (size_t)L_ * H_;            // [10.26M, 15.38M)
    size_t late_base = o;
    float* wj    = ws + o; o += (size_t)B_ * S_;
    float* denom = ws + o; o += B_;
    float* oacc  = ws + o; o += (size_t)B_ * H_;
    float* feat  = ws + o; o += (size_t)B_ * 3 * H_;
    // CSR arrays alias the late region (dead until after k_gather)
    size_t a = late_base;
    int*   cnt    = (int*)(ws + a); a += L_ + 1;
    int*   offs   = (int*)(ws + a); a += L_ + 1;
    int*   cursor = (int*)(ws + a); a += L_ + 1;
    int*   col_s  = (int*)(ws + a); a += EL_;
    float* val_s  = ws + a;         a += EL_;
    // bf16 buffers alias regions dead after k_simwj / k_rnn:
    __bf16* w1bf   = (__bf16*)ws;          // 15.36M bf16 = 7.68M floats over ewu+flags+encw
    __bf16* featbf = (__bf16*)EWW;         // 786K bf16 over EWW (dead after k_rnn)

    hipMemsetAsync(d_ws, 0, zero_elems * sizeof(float), stream);
    hipMemsetAsync(cnt, 0, (L_ + 1) * sizeof(int), stream);
    k_mark<<<(B_ + 255) / 256, 256, 0, stream>>>(user_id, flags);

    // loc-loc graph: CSR build + deterministic gather
    k_hist<<<(EL_ + 255) / 256, 256, 0, stream>>>(row_loc, cnt, EL_);
    k_scan<<<1, 1024, 0, stream>>>(cnt, offs, cursor);
    k_place<<<(EL_ + 255) / 256, 256, 0, stream>>>(row_loc, col_loc, vals_loc,
                                                   cursor, col_s, val_s, EL_);
    k_gather<<<L_, 256, 0, stream>>>(offs, col_s, val_s, enc_emb, encw);

    // user-loc graph: flags-filtered atomic scatter
    k_scatter<<<(EU_ * 32 + 255) / 256, 256, 0, stream>>>(
        row_usr, col_usr, vals_usr, enc_emb, ewu, flags, EU_);

    // EWW = encw @ W_ih^T + (b_ih + b_hh)   (kept f32: protects RNN recurrence accuracy)
    k_gemm<<<dim3((L_ + BM - 1) / BM, (H_ + BN - 1) / BN), 256, 0, stream>>>(
        encw, W_ih, b_ih, b_hh, EWW, L_, H_, H_);
    k_simwj<<<B_, 256, 0, stream>>>(full_seq_map, length, user_id, time_delta,
                                    geo_delta, encw, ewu, wj, denom);
    k_rnn<<<B_ / 4, 1024, 0, stream>>>(EWW, W_hh, full_seq_map, wj, h0g, oacc);
    k_feat<<<B_, 256, 0, stream>>>(oacc, denom, user_id, user_emb, full_seq, wj, emb2, feat);

    // bf16 conversions (after all readers of the aliased regions are done)
    k_cvt<<<((L_ * 3 * H_ / 4) + 255) / 256, 256, 0, stream>>>(
        (const float4*)W1, (bf16x4*)w1bf, L_ * 3 * H_ / 4);
    k_cvt<<<((B_ * 3 * H_ / 4) + 255) / 256, 256, 0, stream>>>(
        (const float4*)feat, (bf16x4*)featbf, B_ * 3 * H_ / 4);

    // out = feat @ W1^T + b1  (bf16 MFMA)
    k_gemm_bf16<<<dim3(B_ / 128, (L_ + 127) / 128), 256, 0, stream>>>(
        featbf, w1bf, b1, out, B_, L_, 3 * H_);
}

// Round 4
// 862.385 us; speedup vs baseline: 5.4144x; 1.1776x over previous
//
#include <hip/hip_runtime.h>
#include <math.h>

#define B_  1024
#define S_  100
#define H_  256
#define L_  20000
#define U_  20000
#define EL_ 500000
#define EU_ 400000

typedef __bf16 bf16x8 __attribute__((ext_vector_type(8)));
typedef __bf16 bf16x4 __attribute__((ext_vector_type(4)));
typedef float  f32x4  __attribute__((ext_vector_type(4)));
typedef _Float16 f16x8 __attribute__((ext_vector_type(8)));

// ---------------- flags for needed user rows ----------------
__global__ void k_mark(const int* __restrict__ uid, int* __restrict__ flags) {
    int i = blockIdx.x * blockDim.x + threadIdx.x;
    if (i < B_) flags[uid[i]] = 1;
}

// ---------------- CSR build: histogram ----------------
__global__ void k_hist(const int* __restrict__ row, int* __restrict__ cnt, int nE) {
    int e = blockIdx.x * blockDim.x + threadIdx.x;
    if (e < nE) atomicAdd(&cnt[row[e]], 1);
}

// ---------------- CSR build: single-block exclusive scan ----------------
__global__ __launch_bounds__(1024) void k_scan(const int* __restrict__ cnt,
                                               int* __restrict__ offs,
                                               int* __restrict__ cursor) {
    __shared__ int wsum[16];
    __shared__ int carry_s;
    int tid = threadIdx.x;
    int lane = tid & 63, wv = tid >> 6;
    if (tid == 0) carry_s = 0;
    __syncthreads();
    for (int base = 0; base < L_; base += 1024) {
        int v = (base + tid < L_) ? cnt[base + tid] : 0;
        int x = v;
#pragma unroll
        for (int off = 1; off < 64; off <<= 1) {
            int y = __shfl_up(x, off, 64);
            if (lane >= off) x += y;
        }
        if (lane == 63) wsum[wv] = x;
        __syncthreads();
        if (wv == 0) {
            int s = (lane < 16) ? wsum[lane] : 0;
#pragma unroll
            for (int off = 1; off < 16; off <<= 1) {
                int y = __shfl_up(s, off, 64);
                if (lane >= off) s += y;
            }
            if (lane < 16) wsum[lane] = s;
        }
        __syncthreads();
        int excl = x - v + (wv ? wsum[wv - 1] : 0) + carry_s;
        if (base + tid < L_) { offs[base + tid] = excl; cursor[base + tid] = excl; }
        __syncthreads();
        if (tid == 0) carry_s += wsum[15];
        __syncthreads();
    }
    if (tid == 0) offs[L_] = carry_s;
}

// ---------------- CSR build: place edges ----------------
__global__ void k_place(const int* __restrict__ row, const int* __restrict__ col,
                        const float* __restrict__ vals, int* __restrict__ cursor,
                        int* __restrict__ col_s, float* __restrict__ val_s, int nE) {
    int e = blockIdx.x * blockDim.x + threadIdx.x;
    if (e >= nE) return;
    int pos = atomicAdd(&cursor[row[e]], 1);
    col_s[pos] = col[e];
    val_s[pos] = vals[e];
}

// ---------------- gather-accumulate: one block per row, no atomics ----------------
__global__ __launch_bounds__(256) void k_gather(const int* __restrict__ offs,
                                                const int* __restrict__ col_s,
                                                const float* __restrict__ val_s,
                                                const float* __restrict__ emb,
                                                float* __restrict__ out) {
    int r = blockIdx.x;
    int tid = threadIdx.x;
    int lo = offs[r], hi = offs[r + 1];
    float acc = 0.f;
    int i = lo;
    for (; i + 1 < hi; i += 2) {
        int c0 = col_s[i], c1 = col_s[i + 1];
        float v0 = val_s[i], v1 = val_s[i + 1];
        float e0 = emb[(long long)c0 * H_ + tid];
        float e1 = emb[(long long)c1 * H_ + tid];
        acc += v0 * e0 + v1 * e1;
    }
    if (i < hi) acc += val_s[i] * emb[(long long)col_s[i] * H_ + tid];
    out[(long long)r * H_ + tid] = acc;
}

// ---------------- COO atomic scatter (user graph, flags-filtered) ----------------
__global__ void k_scatter(const int* __restrict__ row, const int* __restrict__ col,
                          const float* __restrict__ vals, const float* __restrict__ emb,
                          float* __restrict__ out, const int* __restrict__ flags, int nE) {
    long long tid = (long long)blockIdx.x * blockDim.x + threadIdx.x;
    int e = (int)(tid >> 5);
    if (e >= nE) return;
    int r = row[e];
    if (flags && !flags[r]) return;
    int part = (int)(tid & 31);
    int c = col[e];
    float v = vals[e];
    int h0 = part * 8;
    const float4* s4 = (const float4*)(emb + (long long)c * H_ + h0);
    float4 x0 = s4[0], x1 = s4[1];
    float* dst = out + (long long)r * H_ + h0;
    atomicAdd(dst + 0, v * x0.x); atomicAdd(dst + 1, v * x0.y);
    atomicAdd(dst + 2, v * x0.z); atomicAdd(dst + 3, v * x0.w);
    atomicAdd(dst + 4, v * x1.x); atomicAdd(dst + 5, v * x1.y);
    atomicAdd(dst + 6, v * x1.z); atomicAdd(dst + 7, v * x1.w);
}

// ---------------- f32 GEMM (EWW only): C = A @ B^T + bias ----------------
#define BM 128
#define BN 128
#define BK 16
#define PADW 132

__global__ __launch_bounds__(256) void k_gemm(
        const float* __restrict__ A, const float* __restrict__ Bm,
        const float* __restrict__ bias1, const float* __restrict__ bias2,
        float* __restrict__ C, int M, int N, int K) {
    __shared__ float As[BK][PADW];
    __shared__ float Bs[BK][PADW];
    int m0 = blockIdx.x * BM;
    int n0 = blockIdx.y * BN;
    int tid = threadIdx.x;
    int tn = tid & 15, tm = tid >> 4;

    float acc[8][8];
#pragma unroll
    for (int i = 0; i < 8; i++)
#pragma unroll
        for (int j = 0; j < 8; j++) acc[i][j] = 0.f;

    for (int k0 = 0; k0 < K; k0 += BK) {
#pragma unroll
        for (int h = 0; h < 2; h++) {
            int v = tid + h * 256;
            int rw = v >> 2, c4 = v & 3;
            int ar = m0 + rw; if (ar > M - 1) ar = M - 1;
            float4 a = *(const float4*)(A + (long long)ar * K + k0 + c4 * 4);
            As[c4 * 4 + 0][rw] = a.x; As[c4 * 4 + 1][rw] = a.y;
            As[c4 * 4 + 2][rw] = a.z; As[c4 * 4 + 3][rw] = a.w;
            int br = n0 + rw; if (br > N - 1) br = N - 1;
            float4 b = *(const float4*)(Bm + (long long)br * K + k0 + c4 * 4);
            Bs[c4 * 4 + 0][rw] = b.x; Bs[c4 * 4 + 1][rw] = b.y;
            Bs[c4 * 4 + 2][rw] = b.z; Bs[c4 * 4 + 3][rw] = b.w;
        }
        __syncthreads();
#pragma unroll
        for (int kk = 0; kk < BK; kk++) {
            float4 a0 = *(const float4*)&As[kk][tm * 8];
            float4 a1 = *(const float4*)&As[kk][tm * 8 + 4];
            float4 b0 = *(const float4*)&Bs[kk][tn * 8];
            float4 b1 = *(const float4*)&Bs[kk][tn * 8 + 4];
            float av[8] = {a0.x, a0.y, a0.z, a0.w, a1.x, a1.y, a1.z, a1.w};
            float bv[8] = {b0.x, b0.y, b0.z, b0.w, b1.x, b1.y, b1.z, b1.w};
#pragma unroll
            for (int i = 0; i < 8; i++)
#pragma unroll
                for (int j = 0; j < 8; j++) acc[i][j] += av[i] * bv[j];
        }
        __syncthreads();
    }

    float bsum[8];
#pragma unroll
    for (int j = 0; j < 8; j++) {
        int n = n0 + tn * 8 + j;
        float bb = 0.f;
        if (n < N) {
            if (bias1) bb += bias1[n];
            if (bias2) bb += bias2[n];
        }
        bsum[j] = bb;
    }
#pragma unroll
    for (int i = 0; i < 8; i++) {
        int m = m0 + tm * 8 + i;
        if (m < M) {
#pragma unroll
            for (int j = 0; j < 8; j++) {
                int n = n0 + tn * 8 + j;
                if (n < N) C[(long long)m * N + n] = acc[i][j] + bsum[j];
            }
        }
    }
}

// ---------------- f32 -> bf16 conversion (vectorized) ----------------
__global__ __launch_bounds__(256) void k_cvt(const float4* __restrict__ src,
                                             bf16x4* __restrict__ dst, int n4) {
    int i = blockIdx.x * blockDim.x + threadIdx.x;
    if (i >= n4) return;
    float4 v = src[i];
    bf16x4 o;
    o[0] = (__bf16)v.x; o[1] = (__bf16)v.y; o[2] = (__bf16)v.z; o[3] = (__bf16)v.w;
    dst[i] = o;
}

// ---------------- bf16 MFMA GEMM: C[m,n] = A[m,:] . Bw[n,:] + bias[n] ----------------
__global__ __launch_bounds__(256) void k_gemm_bf16(
        const __bf16* __restrict__ A, const __bf16* __restrict__ Bw,
        const float* __restrict__ bias, float* __restrict__ C,
        int M, int N, int K) {
    __shared__ __bf16 Asl[128 * 32];
    __shared__ __bf16 Bsl[128 * 32];
    int tid = threadIdx.x;
    int lane = tid & 63, w = tid >> 6;
    int wm = w >> 1, wn = w & 1;
    int m0 = blockIdx.x * 128, n0 = blockIdx.y * 128;

    f32x4 acc[4][4];
#pragma unroll
    for (int i = 0; i < 4; i++)
#pragma unroll
        for (int j = 0; j < 4; j++) acc[i][j] = (f32x4){0.f, 0.f, 0.f, 0.f};

    int fm = lane & 15, fq = lane >> 4;

    for (int k0 = 0; k0 < K; k0 += 32) {
#pragma unroll
        for (int h = 0; h < 2; h++) {
            int c = h * 256 + w * 64 + lane;
            int r = c >> 2, qsw = c & 3;
            int q = qsw ^ ((r >> 1) & 3);
            const __bf16* gA = A + (long long)(m0 + r) * K + k0 + q * 8;
            __builtin_amdgcn_global_load_lds(
                (const __attribute__((address_space(1))) void*)gA,
                (__attribute__((address_space(3))) void*)(Asl + (h * 256 + w * 64) * 8),
                16, 0, 0);
            int br = n0 + r; if (br > N - 1) br = N - 1;
            const __bf16* gB = Bw + (long long)br * K + k0 + q * 8;
            __builtin_amdgcn_global_load_lds(
                (const __attribute__((address_space(1))) void*)gB,
                (__attribute__((address_space(3))) void*)(Bsl + (h * 256 + w * 64) * 8),
                16, 0, 0);
        }
        __syncthreads();

        bf16x8 af[4], bfr[4];
#pragma unroll
        for (int mi = 0; mi < 4; mi++) {
            int r = wm * 64 + mi * 16 + fm;
            int ch = r * 4 + (fq ^ ((r >> 1) & 3));
            af[mi] = *(const bf16x8*)(Asl + ch * 8);
        }
#pragma unroll
        for (int ni = 0; ni < 4; ni++) {
            int r = wn * 64 + ni * 16 + fm;
            int ch = r * 4 + (fq ^ ((r >> 1) & 3));
            bfr[ni] = *(const bf16x8*)(Bsl + ch * 8);
        }
#pragma unroll
        for (int mi = 0; mi < 4; mi++)
#pragma unroll
            for (int ni = 0; ni < 4; ni++)
                acc[mi][ni] = __builtin_amdgcn_mfma_f32_16x16x32_bf16(
                    af[mi], bfr[ni], acc[mi][ni], 0, 0, 0);
        __syncthreads();
    }

#pragma unroll
    for (int ni = 0; ni < 4; ni++) {
        int col = n0 + wn * 64 + ni * 16 + fm;
        if (col >= N) continue;
        float bb = bias[col];
#pragma unroll
        for (int mi = 0; mi < 4; mi++) {
            int row = m0 + wm * 64 + mi * 16 + fq * 4;
#pragma unroll
            for (int r = 0; r < 4; r++)
                C[(long long)(row + r) * N + col] = acc[mi][ni][r] + bb;
        }
    }
}

// ---------------- w_j and denom ----------------
__global__ __launch_bounds__(256) void k_simwj(
        const int* __restrict__ map, const int* __restrict__ length, const int* __restrict__ uid,
        const float* __restrict__ td_, const float* __restrict__ gd_,
        const float* __restrict__ encw, const float* __restrict__ ewu,
        float* __restrict__ wj, float* __restrict__ denom) {
    int b = blockIdx.x;
    __shared__ float up[H_];
    __shared__ float wjl[S_];
    int tid = threadIdx.x;
    int u = uid[b];
    up[tid] = ewu[(long long)u * H_ + tid];
    __syncthreads();
    int wv = tid >> 6, lane = tid & 63;
    int len = length[b];
    for (int s = wv; s < S_; s += 4) {
        int mi = map[b * S_ + s];
        float4 x = ((const float4*)(encw + (long long)mi * H_))[lane];
        float4 uu = *(const float4*)&up[lane * 4];
        float dx = uu.x - x.x, dy = uu.y - x.y, dz = uu.z - x.z, dw = uu.w - x.w;
        float d2 = dx * dx + dy * dy + dz * dz + dw * dw;
#pragma unroll
        for (int off = 32; off; off >>= 1) d2 += __shfl_xor(d2, off, 64);
        if (lane == 0) {
            float nrm = sqrtf(d2);
            float sim = expf(-nrm);
            float td = td_[b * S_ + s], gd = gd_[b * S_ + s];
            float aj = (cosf(td * 7.27220521664304e-05f) + 1.0f) * 0.5f *
                       expf(-td * 1.1574074074074073e-06f);
            float bj = expf(-gd * 1000.0f);
            float w = (aj * bj + 1e-10f) * sim;
            if (s >= len) w = 0.f;
            wjl[s] = w;
            wj[b * S_ + s] = w;
        }
    }
    __syncthreads();
    if (tid < 64) {
        float v = (tid < S_) ? wjl[tid] : 0.f;
        if (tid + 64 < S_) v += wjl[tid + 64];
#pragma unroll
        for (int off = 32; off; off >>= 1) v += __shfl_xor(v, off, 64);
        if (tid == 0) denom[b] = v;
    }
}

// ---------------- RNN via MFMA: 64 blocks x 16 batch rows, W_hh in B-fragments ----------------
// h_{t+1} = tanh(xw + h_t @ W_hh^T); oacc[b][j] = sum_s wj[b][s] * h_s[b][j]
#define RNN_STRIDE 264   // f16 row stride: 528B = 132 dwords = 4 banks mod 32 -> frag reads hit 8-deep floor

__global__ __launch_bounds__(256, 1) void k_rnn_mfma(
        const float* __restrict__ EWW, const float* __restrict__ Whh,
        const int* __restrict__ map, const float* __restrict__ wj,
        const float* __restrict__ h0g, float* __restrict__ out_acc) {
    __shared__ _Float16 hbuf[16 * RNN_STRIDE];
    __shared__ int   maps_s[S_ * 16];
    __shared__ float wjs_s[S_ * 16];

    int tid = threadIdx.x;
    int lane = tid & 63, w = tid >> 6;
    int fm = lane & 15, fq = lane >> 4;
    int b0 = blockIdx.x * 16;

    // stage maps & wj for this block's 16 rows x 100 steps
    for (int i = tid; i < 16 * S_; i += 256) {
        int m = i / S_, s = i - m * S_;
        maps_s[s * 16 + m] = map[(b0 + m) * S_ + s];
        wjs_s[s * 16 + m] = wj[(b0 + m) * S_ + s];
    }
    // stage h0 -> f16 A-layout hbuf[m][k]
    {
        int m = tid >> 4, seg = tid & 15;
        const float4* src = (const float4*)(h0g + (long long)(b0 + m) * H_ + seg * 16);
        float4 a = src[0], bq = src[1], cq = src[2], dq = src[3];
        f16x8 v0, v1;
        v0[0] = (_Float16)a.x;  v0[1] = (_Float16)a.y;  v0[2] = (_Float16)a.z;  v0[3] = (_Float16)a.w;
        v0[4] = (_Float16)bq.x; v0[5] = (_Float16)bq.y; v0[6] = (_Float16)bq.z; v0[7] = (_Float16)bq.w;
        v1[0] = (_Float16)cq.x; v1[1] = (_Float16)cq.y; v1[2] = (_Float16)cq.z; v1[3] = (_Float16)cq.w;
        v1[4] = (_Float16)dq.x; v1[5] = (_Float16)dq.y; v1[6] = (_Float16)dq.z; v1[7] = (_Float16)dq.w;
        *(f16x8*)(hbuf + m * RNN_STRIDE + seg * 16) = v0;
        *(f16x8*)(hbuf + m * RNN_STRIDE + seg * 16 + 8) = v1;
    }

    // W_hh B-fragments in registers: wf[ni][c], B[n=fm][k=c*32+fq*8+j], n_global = w*64+ni*16+fm
    f16x8 wf[4][8];
#pragma unroll
    for (int ni = 0; ni < 4; ni++) {
        const float* wrow = Whh + (long long)(w * 64 + ni * 16 + fm) * H_;
#pragma unroll
        for (int c = 0; c < 8; c++) {
            int k = c * 32 + fq * 8;
            float4 p = *(const float4*)(wrow + k);
            float4 q = *(const float4*)(wrow + k + 4);
            f16x8 v;
            v[0] = (_Float16)p.x; v[1] = (_Float16)p.y; v[2] = (_Float16)p.z; v[3] = (_Float16)p.w;
            v[4] = (_Float16)q.x; v[5] = (_Float16)q.y; v[6] = (_Float16)q.z; v[7] = (_Float16)q.w;
            wf[ni][c] = v;
        }
    }

    float accv[4][4];
#pragma unroll
    for (int ni = 0; ni < 4; ni++)
#pragma unroll
        for (int r = 0; r < 4; r++) accv[ni][r] = 0.f;

    __syncthreads();   // maps/wj/h0 staged

    // prefetch x for s=0 (C-layout positions; bias already folded into EWW)
    float xc[4][4], xn[4][4];
#pragma unroll
    for (int r = 0; r < 4; r++) {
        const float* xp = EWW + (long long)maps_s[0 * 16 + fq * 4 + r] * H_;
#pragma unroll
        for (int ni = 0; ni < 4; ni++) xc[ni][r] = xp[w * 64 + ni * 16 + fm];
    }

    for (int s = 0; s < S_; s++) {
        f32x4 acc[4];
#pragma unroll
        for (int ni = 0; ni < 4; ni++)
            acc[ni] = (f32x4){xc[ni][0], xc[ni][1], xc[ni][2], xc[ni][3]};

        if (s + 1 < S_) {
#pragma unroll
            for (int r = 0; r < 4; r++) {
                const float* xp = EWW + (long long)maps_s[(s + 1) * 16 + fq * 4 + r] * H_;
#pragma unroll
                for (int ni = 0; ni < 4; ni++) xn[ni][r] = xp[w * 64 + ni * 16 + fm];
            }
        }

        f16x8 af[8];
#pragma unroll
        for (int c = 0; c < 8; c++)
            af[c] = *(const f16x8*)(hbuf + fm * RNN_STRIDE + c * 32 + fq * 8);
#pragma unroll
        for (int c = 0; c < 8; c++)
#pragma unroll
            for (int ni = 0; ni < 4; ni++)
                acc[ni] = __builtin_amdgcn_mfma_f32_16x16x32_f16(af[c], wf[ni][c], acc[ni], 0, 0, 0);
        __syncthreads();   // all waves' hbuf reads complete

        float wjr[4];
#pragma unroll
        for (int r = 0; r < 4; r++) wjr[r] = wjs_s[s * 16 + fq * 4 + r];
#pragma unroll
        for (int ni = 0; ni < 4; ni++) {
#pragma unroll
            for (int r = 0; r < 4; r++) {
                float t = acc[ni][r];
                t = fminf(15.f, fmaxf(-15.f, t));
                float e = __expf(2.f * t);
                float hv = 1.f - 2.f / (e + 1.f);
                accv[ni][r] += wjr[r] * hv;
                hbuf[(fq * 4 + r) * RNN_STRIDE + w * 64 + ni * 16 + fm] = (_Float16)hv;
            }
        }
        __syncthreads();   // h writes visible before next step's frag reads

#pragma unroll
        for (int ni = 0; ni < 4; ni++)
#pragma unroll
            for (int r = 0; r < 4; r++) xc[ni][r] = xn[ni][r];
    }

#pragma unroll
    for (int ni = 0; ni < 4; ni++)
#pragma unroll
        for (int r = 0; r < 4; r++)
            out_acc[(long long)(b0 + fq * 4 + r) * H_ + w * 64 + ni * 16 + fm] = accv[ni][r];
}

// ---------------- feature build: [out_w, p_u, out_w2] ----------------
__global__ __launch_bounds__(256) void k_feat(
        const float* __restrict__ out_acc, const float* __restrict__ denom,
        const int* __restrict__ uid, const float* __restrict__ user_emb,
        const int* __restrict__ seq, const float* __restrict__ wj,
        const float* __restrict__ emb2, float* __restrict__ feat) {
    int b = blockIdx.x, j = threadIdx.x;
    __shared__ float wjl[S_];
    __shared__ int sq[S_];
    if (j < S_) {
        wjl[j] = wj[b * S_ + j];
        sq[j] = seq[b * S_ + j];
    }
    __syncthreads();
    float inv = 1.f / denom[b];
    feat[(long long)b * 768 + j] = out_acc[(long long)b * H_ + j] * inv;
    feat[(long long)b * 768 + 256 + j] = user_emb[(long long)uid[b] * H_ + j];
    float a2 = 0.f;
    for (int s = 0; s < S_; s++) a2 += wjl[s] * emb2[(long long)sq[s] * H_ + j];
    feat[(long long)b * 768 + 512 + j] = a2 * inv;
}

extern "C" void kernel_launch(void* const* d_in, const int* in_sizes, int n_in,
                              void* d_out, int out_size, void* d_ws, size_t ws_size,
                              hipStream_t stream) {
    const int*   full_seq     = (const int*)d_in[0];
    const int*   full_seq_map = (const int*)d_in[1];
    const int*   length       = (const int*)d_in[2];
    const int*   user_id      = (const int*)d_in[3];
    const float* time_delta   = (const float*)d_in[4];
    const float* geo_delta    = (const float*)d_in[5];
    const float* enc_emb      = (const float*)d_in[6];
    const float* user_emb     = (const float*)d_in[7];
    const float* emb2         = (const float*)d_in[8];
    const int*   row_loc      = (const int*)d_in[9];
    const int*   col_loc      = (const int*)d_in[10];
    const float* vals_loc     = (const float*)d_in[11];
    const int*   row_usr      = (const int*)d_in[12];
    const int*   col_usr      = (const int*)d_in[13];
    const float* vals_usr     = (const float*)d_in[14];
    const float* W_ih         = (const float*)d_in[15];
    const float* W_hh         = (const float*)d_in[16];
    const float* b_ih         = (const float*)d_in[17];
    const float* b_hh         = (const float*)d_in[18];
    const float* W1           = (const float*)d_in[19];
    const float* b1           = (const float*)d_in[20];
    const float* h0g          = (const float*)d_in[21];
    float* out = (float*)d_out;

    float* ws = (float*)d_ws;
    size_t o = 0;
    float* ewu   = ws + o; o += (size_t)U_ * H_;
    int*   flags = (int*)(ws + o); o += U_;
    size_t zero_elems = o;
    float* encw  = ws + o; o += (size_t)L_ * H_;
    float* EWW   = ws + o; o += (size_t)L_ * H_;
    size_t late_base = o;
    float* wj    = ws + o; o += (size_t)B_ * S_;
    float* denom = ws + o; o += B_;
    float* oacc  = ws + o; o += (size_t)B_ * H_;
    float* feat  = ws + o; o += (size_t)B_ * 3 * H_;
    size_t a = late_base;
    int*   cnt    = (int*)(ws + a); a += L_ + 1;
    int*   offs   = (int*)(ws + a); a += L_ + 1;
    int*   cursor = (int*)(ws + a); a += L_ + 1;
    int*   col_s  = (int*)(ws + a); a += EL_;
    float* val_s  = ws + a;         a += EL_;
    __bf16* w1bf   = (__bf16*)ws;
    __bf16* featbf = (__bf16*)EWW;

    hipMemsetAsync(d_ws, 0, zero_elems * sizeof(float), stream);
    hipMemsetAsync(cnt, 0, (L_ + 1) * sizeof(int), stream);
    k_mark<<<(B_ + 255) / 256, 256, 0, stream>>>(user_id, flags);

    k_hist<<<(EL_ + 255) / 256, 256, 0, stream>>>(row_loc, cnt, EL_);
    k_scan<<<1, 1024, 0, stream>>>(cnt, offs, cursor);
    k_place<<<(EL_ + 255) / 256, 256, 0, stream>>>(row_loc, col_loc, vals_loc,
                                                   cursor, col_s, val_s, EL_);
    k_gather<<<L_, 256, 0, stream>>>(offs, col_s, val_s, enc_emb, encw);

    k_scatter<<<(EU_ * 32 + 255) / 256, 256, 0, stream>>>(
        row_usr, col_usr, vals_usr, enc_emb, ewu, flags, EU_);

    k_gemm<<<dim3((L_ + BM - 1) / BM, (H_ + BN - 1) / BN), 256, 0, stream>>>(
        encw, W_ih, b_ih, b_hh, EWW, L_, H_, H_);
    k_simwj<<<B_, 256, 0, stream>>>(full_seq_map, length, user_id, time_delta,
                                    geo_delta, encw, ewu, wj, denom);
    k_rnn_mfma<<<B_ / 16, 256, 0, stream>>>(EWW, W_hh, full_seq_map, wj, h0g, oacc);
    k_feat<<<B_, 256, 0, stream>>>(oacc, denom, user_id, user_emb, full_seq, wj, emb2, feat);

    k_cvt<<<((L_ * 3 * H_ / 4) + 255) / 256, 256, 0, stream>>>(
        (const float4*)W1, (bf16x4*)w1bf, L_ * 3 * H_ / 4);
    k_cvt<<<((B_ * 3 * H_ / 4) + 255) / 256, 256, 0, stream>>>(
        (const float4*)feat, (bf16x4*)featbf, B_ * 3 * H_ / 4);

    k_gemm_bf16<<<dim3(B_ / 128, (L_ + 127) / 128), 256, 0, stream>>>(
        featbf, w1bf, b1, out, B_, L_, 3 * H_);
}